// Round 1
// baseline (10443.004 us; speedup 1.0000x reference)
//
#include <hip/hip_runtime.h>

#define BATCH 16
#define NROW  256
#define MCOL  256
#define CDIM  4096
#define INF_F 1e30f

// ---------------------------------------------------------------------------
// Kernel 1: per-(b,n) softmax stats over C=4096: row max and sum(exp(x-max))
// ---------------------------------------------------------------------------
__global__ __launch_bounds__(256)
void softmax_stats_kernel(const float* __restrict__ logits,
                          float* __restrict__ row_max,
                          float* __restrict__ row_sum) {
    const int row = blockIdx.x;                 // 0 .. B*N-1
    const float* rp = logits + (size_t)row * CDIM;
    const int t = threadIdx.x;                  // 256 threads
    const int lane = t & 63, wave = t >> 6;

    __shared__ float part[4];
    __shared__ float bcast;

    // max
    float mx = -INF_F;
    for (int c = t; c < CDIM; c += 256) mx = fmaxf(mx, rp[c]);
    for (int off = 32; off; off >>= 1) mx = fmaxf(mx, __shfl_down(mx, off));
    if (lane == 0) part[wave] = mx;
    __syncthreads();
    if (t == 0) bcast = fmaxf(fmaxf(part[0], part[1]), fmaxf(part[2], part[3]));
    __syncthreads();
    mx = bcast;

    // sum exp
    float s = 0.f;
    for (int c = t; c < CDIM; c += 256) s += expf(rp[c] - mx);
    for (int off = 32; off; off >>= 1) s += __shfl_down(s, off);
    __syncthreads();
    if (lane == 0) part[wave] = s;
    __syncthreads();
    if (t == 0) {
        row_max[row] = mx;
        row_sum[row] = part[0] + part[1] + part[2] + part[3];
    }
}

// ---------------------------------------------------------------------------
// Kernel 2: cost[b,n,m] = -softmax(logits[b,n])[lbl[b,m]] + 5 * L1(p[b,n], g[b,m])
// ---------------------------------------------------------------------------
__global__ __launch_bounds__(256)
void cost_kernel(const float* __restrict__ pred_ctrl,
                 const float* __restrict__ logits,
                 const float* __restrict__ gt_ctrl,
                 const int* __restrict__ gt_labels,
                 const float* __restrict__ row_max,
                 const float* __restrict__ row_sum,
                 float* __restrict__ Cout) {
    const int bn = blockIdx.x;                  // b*N + n
    const int b  = bn >> 8;
    const int m  = threadIdx.x;                 // 0..255

    const float* pp = pred_ctrl + (size_t)bn * 8;
    const float p0 = pp[0], p1 = pp[1], p2 = pp[2], p3 = pp[3];
    const float p4 = pp[4], p5 = pp[5], p6 = pp[6], p7 = pp[7];

    const float* gp = gt_ctrl + ((size_t)b * MCOL + m) * 8;
    const float4 ga = *(const float4*)gp;
    const float4 gb = *(const float4*)(gp + 4);

    const int lbl = gt_labels[b * MCOL + m];
    const float l = logits[(size_t)bn * CDIM + lbl];
    const float prob = expf(l - row_max[bn]) / row_sum[bn];

    float cb = fabsf(p0 - ga.x);
    cb += fabsf(p1 - ga.y);
    cb += fabsf(p2 - ga.z);
    cb += fabsf(p3 - ga.w);
    cb += fabsf(p4 - gb.x);
    cb += fabsf(p5 - gb.y);
    cb += fabsf(p6 - gb.z);
    cb += fabsf(p7 - gb.w);

    Cout[(size_t)bn * MCOL + m] = -prob + 5.0f * cb;
}

// ---------------------------------------------------------------------------
// Kernel 3: Jonker-Volgenant shortest augmenting path, one wave per batch.
// Lane t owns columns {t, t+64, t+128, t+192} and rows likewise.
// Mirrors the reference lax.scan/while_loop structure exactly.
// ---------------------------------------------------------------------------
__global__ __launch_bounds__(64)
void lsa_kernel(const float* __restrict__ Cmat,
                float* __restrict__ out_row,
                float* __restrict__ out_col) {
    const int b = blockIdx.x;
    const int t = threadIdx.x;
    const float* C = Cmat + (size_t)b * NROW * MCOL;

    __shared__ float u[NROW], v[MCOL], spc[MCOL];
    __shared__ int   path[MCOL], row4col[MCOL], col4row[NROW];
    __shared__ unsigned char SC[MCOL], SR[NROW];

    for (int k = 0; k < 4; k++) {
        const int j = t + 64 * k;
        u[j] = 0.f; v[j] = 0.f; row4col[j] = -1; col4row[j] = -1;
    }
    __syncthreads();

    for (int cur = 0; cur < NROW; cur++) {
        // per-row search init
        for (int k = 0; k < 4; k++) {
            const int j = t + 64 * k;
            spc[j] = INF_F; path[j] = -1; SC[j] = 0; SR[j] = 0;
        }
        int i = cur;
        float minVal = 0.f;
        int sink = -1;
        __syncthreads();

        // Dijkstra-style shortest augmenting path
        for (int iter = 0; iter < MCOL && sink < 0; iter++) {
            if (t == 0) SR[i] = 1;
            const float ui = u[i];
            const float* crow = C + (size_t)i * MCOL;

            for (int k = 0; k < 4; k++) {
                const int j = t + 64 * k;
                if (!SC[j]) {
                    const float r = ((minVal + crow[j]) - ui) - v[j];
                    if (r < spc[j]) { spc[j] = r; path[j] = i; }
                }
            }
            __syncthreads();

            // argmin over masked spc, lowest index on ties (matches jnp.argmin)
            float mv = INF_F; int mj = MCOL;
            for (int k = 0; k < 4; k++) {
                const int j = t + 64 * k;
                const float val = SC[j] ? INF_F : spc[j];
                if (val < mv || (val == mv && j < mj)) { mv = val; mj = j; }
            }
            for (int off = 32; off; off >>= 1) {
                const float ov = __shfl_down(mv, off);
                const int   oj = __shfl_down(mj, off);
                if (ov < mv || (ov == mv && oj < mj)) { mv = ov; mj = oj; }
            }
            mv = __shfl(mv, 0);
            mj = __shfl(mj, 0);

            minVal = mv;
            if (t == 0) SC[mj] = 1;
            const int r4c = row4col[mj];
            if (r4c < 0) sink = mj; else i = r4c;
            __syncthreads();
        }

        // dual updates (before augmenting, like the reference)
        for (int k = 0; k < 4; k++) {
            const int ri = t + 64 * k;
            if (SR[ri]) {
                if (ri == cur) u[ri] = u[ri] + minVal;
                else           u[ri] = (u[ri] + minVal) - spc[col4row[ri]];
            }
            const int j = ri;
            if (SC[j]) v[j] = v[j] - (minVal - spc[j]);
        }
        __syncthreads();

        // augment along predecessor path (scalar)
        if (t == 0) {
            int j = sink;
            while (true) {
                const int ii = path[j];
                row4col[j] = ii;
                const int jn = col4row[ii];
                col4row[ii] = j;
                if (ii == cur) break;
                j = jn;
            }
        }
        __syncthreads();
    }

    for (int k = 0; k < 4; k++) {
        const int idx = t + 64 * k;
        out_row[b * NROW + idx] = (float)idx;
        out_col[b * NROW + idx] = (float)col4row[idx];
    }
}

// ---------------------------------------------------------------------------
extern "C" void kernel_launch(void* const* d_in, const int* in_sizes, int n_in,
                              void* d_out, int out_size, void* d_ws, size_t ws_size,
                              hipStream_t stream) {
    const float* pred_ctrl   = (const float*)d_in[0];
    const float* pred_logits = (const float*)d_in[1];
    const float* gt_ctrl     = (const float*)d_in[2];
    const int*   gt_labels   = (const int*)d_in[3];

    float* out     = (float*)d_out;
    float* out_row = out;                        // (B,N) row indices as float
    float* out_col = out + BATCH * NROW;         // (B,N) col indices as float
    float* Cout    = out + 2 * BATCH * NROW;     // (B,N,M) cost matrix

    float* row_max = (float*)d_ws;               // B*N floats
    float* row_sum = row_max + BATCH * NROW;     // B*N floats

    softmax_stats_kernel<<<BATCH * NROW, 256, 0, stream>>>(pred_logits, row_max, row_sum);
    cost_kernel<<<BATCH * NROW, 256, 0, stream>>>(pred_ctrl, pred_logits, gt_ctrl,
                                                  gt_labels, row_max, row_sum, Cout);
    lsa_kernel<<<BATCH, 64, 0, stream>>>(Cout, out_row, out_col);
}

// Round 2
// 2602.973 us; speedup vs baseline: 4.0120x; 4.0120x over previous
//
#include <hip/hip_runtime.h>

#define BATCH 16
#define NROW  256
#define MCOL  256
#define CDIM  4096
#define INF_F 1e30f

// ---------------------------------------------------------------------------
// Kernel 1: per-(b,n) softmax stats over C=4096: row max and sum(exp(x-max))
// ---------------------------------------------------------------------------
__global__ __launch_bounds__(256)
void softmax_stats_kernel(const float* __restrict__ logits,
                          float* __restrict__ row_max,
                          float* __restrict__ row_sum) {
    const int row = blockIdx.x;
    const float* rp = logits + (size_t)row * CDIM;
    const int t = threadIdx.x;
    const int lane = t & 63, wave = t >> 6;

    __shared__ float part[4];
    __shared__ float bcast;

    float mx = -INF_F;
    for (int c = t; c < CDIM; c += 256) mx = fmaxf(mx, rp[c]);
    for (int off = 32; off; off >>= 1) mx = fmaxf(mx, __shfl_down(mx, off));
    if (lane == 0) part[wave] = mx;
    __syncthreads();
    if (t == 0) bcast = fmaxf(fmaxf(part[0], part[1]), fmaxf(part[2], part[3]));
    __syncthreads();
    mx = bcast;

    float s = 0.f;
    for (int c = t; c < CDIM; c += 256) s += expf(rp[c] - mx);
    for (int off = 32; off; off >>= 1) s += __shfl_down(s, off);
    __syncthreads();
    if (lane == 0) part[wave] = s;
    __syncthreads();
    if (t == 0) {
        row_max[row] = mx;
        row_sum[row] = part[0] + part[1] + part[2] + part[3];
    }
}

// ---------------------------------------------------------------------------
// Kernel 2: cost[b,n,m] = -softmax(logits[b,n])[lbl[b,m]] + 5 * L1(p[b,n], g[b,m])
// ---------------------------------------------------------------------------
__global__ __launch_bounds__(256)
void cost_kernel(const float* __restrict__ pred_ctrl,
                 const float* __restrict__ logits,
                 const float* __restrict__ gt_ctrl,
                 const int* __restrict__ gt_labels,
                 const float* __restrict__ row_max,
                 const float* __restrict__ row_sum,
                 float* __restrict__ Cout) {
    const int bn = blockIdx.x;
    const int b  = bn >> 8;
    const int m  = threadIdx.x;

    const float* pp = pred_ctrl + (size_t)bn * 8;
    const float p0 = pp[0], p1 = pp[1], p2 = pp[2], p3 = pp[3];
    const float p4 = pp[4], p5 = pp[5], p6 = pp[6], p7 = pp[7];

    const float* gp = gt_ctrl + ((size_t)b * MCOL + m) * 8;
    const float4 ga = *(const float4*)gp;
    const float4 gb = *(const float4*)(gp + 4);

    const int lbl = gt_labels[b * MCOL + m];
    const float l = logits[(size_t)bn * CDIM + lbl];
    const float prob = expf(l - row_max[bn]) / row_sum[bn];

    float cb = fabsf(p0 - ga.x);
    cb += fabsf(p1 - ga.y);
    cb += fabsf(p2 - ga.z);
    cb += fabsf(p3 - ga.w);
    cb += fabsf(p4 - gb.x);
    cb += fabsf(p5 - gb.y);
    cb += fabsf(p6 - gb.z);
    cb += fabsf(p7 - gb.w);

    Cout[(size_t)bn * MCOL + m] = -prob + 5.0f * cb;
}

// ---------------------------------------------------------------------------
// Order-preserving float <-> uint mapping (no NaNs in this data)
// ---------------------------------------------------------------------------
__device__ __forceinline__ unsigned ordkey(float f) {
    unsigned b = __float_as_uint(f);
    return (b & 0x80000000u) ? ~b : (b | 0x80000000u);
}
__device__ __forceinline__ float unordkey(unsigned k) {
    unsigned b = (k & 0x80000000u) ? (k ^ 0x80000000u) : ~k;
    return __uint_as_float(b);
}
__device__ __forceinline__ unsigned long long min64(unsigned long long a, unsigned long long b) {
    return a < b ? a : b;
}
__device__ __forceinline__ unsigned long long max64(unsigned long long a, unsigned long long b) {
    return a > b ? a : b;
}

// ---------------------------------------------------------------------------
// Kernel 3: lapjv-style LSA, one wave per batch.
// Lane t owns columns AND rows [4t .. 4t+3].
//   Init: column reduction (v[j]=colmin, greedy tight match)
//       + budget-capped augmenting row reduction (maintains feasibility+CS)
//   Then: shortest augmenting path phases for remaining free rows
//         (same dual/argmin math as the reference -> same unique optimum).
// ---------------------------------------------------------------------------
__global__ __launch_bounds__(64)
void lsa_kernel(const float* __restrict__ Cmat,
                float* __restrict__ out_row,
                float* __restrict__ out_col) {
    const int b = blockIdx.x;
    const int t = threadIdx.x;
    const int jb = 4 * t;
    const float* C = Cmat + (size_t)b * NROW * MCOL;

    __shared__ float u_s[NROW];
    __shared__ int row4col_s[MCOL];
    __shared__ int col4row_s[NROW];
    __shared__ int path_s[MCOL];
    __shared__ int queue_s[NROW];
    __shared__ int argrow_s[MCOL];
    __shared__ int nfree_s;

    // ---------------- column reduction ----------------
    float m0 = INF_F, m1 = INF_F, m2 = INF_F, m3 = INF_F;
    int   r0 = 0, r1 = 0, r2 = 0, r3 = 0;
    for (int i = 0; i < NROW; i++) {
        const float4 c4 = *(const float4*)(C + (size_t)i * MCOL + jb);
        if (c4.x < m0) { m0 = c4.x; r0 = i; }
        if (c4.y < m1) { m1 = c4.y; r1 = i; }
        if (c4.z < m2) { m2 = c4.z; r2 = i; }
        if (c4.w < m3) { m3 = c4.w; r3 = i; }
    }
    float v0 = m0, v1 = m1, v2 = m2, v3 = m3;   // v[j] in registers (owner lane)

    argrow_s[jb + 0] = r0; argrow_s[jb + 1] = r1;
    argrow_s[jb + 2] = r2; argrow_s[jb + 3] = r3;
    for (int k = 0; k < 4; k++) {
        u_s[jb + k] = 0.f;
        row4col_s[jb + k] = -1;
        col4row_s[jb + k] = -1;
        path_s[jb + k] = -1;
    }
    __syncthreads();

    if (t == 0) {
        for (int j = 0; j < MCOL; j++) {
            const int r = argrow_s[j];
            if (col4row_s[r] < 0) { col4row_s[r] = j; row4col_s[j] = r; }
        }
        int nf = 0;
        for (int i = 0; i < NROW; i++)
            if (col4row_s[i] < 0) queue_s[nf++] = i;
        nfree_s = nf;
    }
    __syncthreads();

    // ---------------- augmenting row reduction (budget-capped) ----------------
    {
        const int nfr = nfree_s;
        int budget = 8 * NROW;
        for (int qi = 0; qi < nfr; qi++) {
            int i = queue_s[qi];
            while (i >= 0 && budget > 0) {
                budget--;
                const float4 c4 = *(const float4*)(C + (size_t)i * MCOL + jb);
                const float d0 = c4.x - v0, d1 = c4.y - v1;
                const float d2 = c4.z - v2, d3 = c4.w - v3;
                const unsigned long long K0 = ((unsigned long long)ordkey(d0) << 32) | (unsigned)(jb + 0);
                const unsigned long long K1 = ((unsigned long long)ordkey(d1) << 32) | (unsigned)(jb + 1);
                const unsigned long long K2 = ((unsigned long long)ordkey(d2) << 32) | (unsigned)(jb + 2);
                const unsigned long long K3 = ((unsigned long long)ordkey(d3) << 32) | (unsigned)(jb + 3);
                const unsigned long long lo01 = min64(K0, K1), hi01 = max64(K0, K1);
                const unsigned long long lo23 = min64(K2, K3), hi23 = max64(K2, K3);
                unsigned long long kmin = min64(lo01, lo23);
                unsigned m2u = (unsigned)(min64(max64(lo01, lo23), min64(hi01, hi23)) >> 32);
                for (int off = 32; off; off >>= 1) {
                    const unsigned long long ok = __shfl_xor(kmin, off);
                    const unsigned om2 = __shfl_xor(m2u, off);
                    const unsigned vmax = (unsigned)(max64(ok, kmin) >> 32);
                    unsigned mn2 = m2u < om2 ? m2u : om2;
                    m2u = vmax < mn2 ? vmax : mn2;
                    if (ok < kmin) kmin = ok;
                }
                const int j1 = (int)(kmin & 0xffffffffu);
                const float mu1 = unordkey((unsigned)(kmin >> 32));
                const float mu2 = unordkey(m2u);

                if (t == 0) u_s[i] = mu2;
                if (mu2 > mu1) {
                    const int ow = j1 >> 2, sl = j1 & 3;
                    if (t == ow) {
                        const float dv = mu2 - mu1;
                        if (sl == 0) v0 -= dv; else if (sl == 1) v1 -= dv;
                        else if (sl == 2) v2 -= dv; else v3 -= dv;
                    }
                }
                const int kold = row4col_s[j1];   // broadcast read BEFORE write
                if (t == 0) {
                    row4col_s[j1] = i;
                    col4row_s[i] = j1;
                    if (kold >= 0) col4row_s[kold] = -1;
                }
                i = kold;      // continue chain with displaced row (or -1 done)
                __syncthreads();
            }
        }
    }
    __syncthreads();

    // rebuild free list; reset duals of free rows (feasible: c - 0 - v >= 0)
    if (t == 0) {
        int nf = 0;
        for (int i = 0; i < NROW; i++)
            if (col4row_s[i] < 0) { queue_s[nf++] = i; u_s[i] = 0.f; }
        nfree_s = nf;
    }
    __syncthreads();

    // ---------------- shortest augmenting path phases ----------------
    const int nphase = nfree_s;
    for (int ph = 0; ph < nphase; ph++) {
        const int cur = queue_s[ph];

        // refresh row4col register mirror for owned columns
        const int4 rcq = *(const int4*)&row4col_s[jb];
        int rc0 = rcq.x, rc1 = rcq.y, rc2 = rcq.z, rc3 = rcq.w;

        float s0 = INF_F, s1 = INF_F, s2 = INF_F, s3 = INF_F;  // spc (owned cols)
        int scmask = 0;                                        // SC for owned cols
        int srmask = 0;                                        // SR for owned rows
        float e0 = 0.f, e1 = 0.f, e2 = 0.f, e3 = 0.f;          // entering minVal per owned row
        int i = cur;
        float minVal = 0.f;
        int sink = -1;

        for (int it = 0; it < MCOL && sink < 0; it++) {
            if ((i >> 2) == t) srmask |= 1 << (i & 3);
            const float ui = u_s[i];
            const float4 c4 = *(const float4*)(C + (size_t)i * MCOL + jb);
            const float base = minVal - ui;
            float d;
            d = base + c4.x - v0; if (!(scmask & 1) && d < s0) { s0 = d; path_s[jb + 0] = i; }
            d = base + c4.y - v1; if (!(scmask & 2) && d < s1) { s1 = d; path_s[jb + 1] = i; }
            d = base + c4.z - v2; if (!(scmask & 4) && d < s2) { s2 = d; path_s[jb + 2] = i; }
            d = base + c4.w - v3; if (!(scmask & 8) && d < s3) { s3 = d; path_s[jb + 3] = i; }

            unsigned long long K = ~0ull;
            if (!(scmask & 1)) { const unsigned long long Kc = ((unsigned long long)ordkey(s0) << 32) | (unsigned)(jb + 0); if (Kc < K) K = Kc; }
            if (!(scmask & 2)) { const unsigned long long Kc = ((unsigned long long)ordkey(s1) << 32) | (unsigned)(jb + 1); if (Kc < K) K = Kc; }
            if (!(scmask & 4)) { const unsigned long long Kc = ((unsigned long long)ordkey(s2) << 32) | (unsigned)(jb + 2); if (Kc < K) K = Kc; }
            if (!(scmask & 8)) { const unsigned long long Kc = ((unsigned long long)ordkey(s3) << 32) | (unsigned)(jb + 3); if (Kc < K) K = Kc; }
            for (int off = 32; off; off >>= 1) {
                const unsigned long long o = __shfl_xor(K, off);
                if (o < K) K = o;
            }
            const int mj = (int)(K & 0xffffffffu);
            minVal = unordkey((unsigned)(K >> 32));

            const int ow = mj >> 2, sl = mj & 3;
            if (t == ow) scmask |= 1 << sl;
            const int rcsel = sl == 0 ? rc0 : sl == 1 ? rc1 : sl == 2 ? rc2 : rc3;
            const int rc = __shfl(rcsel, ow);
            if (rc < 0) {
                sink = mj;
            } else {
                i = rc;
                if ((rc >> 2) == t) {   // record entering value for row rc
                    const int s = rc & 3;
                    if (s == 0) e0 = minVal; else if (s == 1) e1 = minVal;
                    else if (s == 2) e2 = minVal; else e3 = minVal;
                }
            }
        }

        // dual updates (owned rows / owned cols), same formulas as reference
        if (srmask & 1) { const int ri = jb + 0; u_s[ri] += (ri == cur) ? minVal : (minVal - e0); }
        if (srmask & 2) { const int ri = jb + 1; u_s[ri] += (ri == cur) ? minVal : (minVal - e1); }
        if (srmask & 4) { const int ri = jb + 2; u_s[ri] += (ri == cur) ? minVal : (minVal - e2); }
        if (srmask & 8) { const int ri = jb + 3; u_s[ri] += (ri == cur) ? minVal : (minVal - e3); }
        if (scmask & 1) v0 -= (minVal - s0);
        if (scmask & 2) v1 -= (minVal - s1);
        if (scmask & 4) v2 -= (minVal - s2);
        if (scmask & 8) v3 -= (minVal - s3);

        __syncthreads();
        if (t == 0) {
            int j = sink;
            while (true) {
                const int ii = path_s[j];
                row4col_s[j] = ii;
                const int jn = col4row_s[ii];
                col4row_s[ii] = j;
                if (ii == cur) break;
                j = jn;
            }
        }
        __syncthreads();
    }

    for (int k = 0; k < 4; k++) {
        const int idx = jb + k;
        out_row[b * NROW + idx] = (float)idx;
        out_col[b * NROW + idx] = (float)col4row_s[idx];
    }
}

// ---------------------------------------------------------------------------
extern "C" void kernel_launch(void* const* d_in, const int* in_sizes, int n_in,
                              void* d_out, int out_size, void* d_ws, size_t ws_size,
                              hipStream_t stream) {
    const float* pred_ctrl   = (const float*)d_in[0];
    const float* pred_logits = (const float*)d_in[1];
    const float* gt_ctrl     = (const float*)d_in[2];
    const int*   gt_labels   = (const int*)d_in[3];

    float* out     = (float*)d_out;
    float* out_row = out;
    float* out_col = out + BATCH * NROW;
    float* Cout    = out + 2 * BATCH * NROW;

    float* row_max = (float*)d_ws;
    float* row_sum = row_max + BATCH * NROW;

    softmax_stats_kernel<<<BATCH * NROW, 256, 0, stream>>>(pred_logits, row_max, row_sum);
    cost_kernel<<<BATCH * NROW, 256, 0, stream>>>(pred_ctrl, pred_logits, gt_ctrl,
                                                  gt_labels, row_max, row_sum, Cout);
    lsa_kernel<<<BATCH, 64, 0, stream>>>(Cout, out_row, out_col);
}

// Round 3
// 2236.446 us; speedup vs baseline: 4.6695x; 1.1639x over previous
//
#include <hip/hip_runtime.h>

#define BATCH 16
#define NROW  256
#define MCOL  256
#define CDIM  4096
#define INF_F 1e30f

// ---------------------------------------------------------------------------
// Fused cost kernel: per-(b,n) softmax stats over C=4096, then 256 cost cols.
// cost[b,n,m] = -softmax(logits[b,n])[lbl[b,m]] + 5 * L1(p[b,n], g[b,m])
// ---------------------------------------------------------------------------
__global__ __launch_bounds__(256)
void cost_fused_kernel(const float* __restrict__ pred_ctrl,
                       const float* __restrict__ logits,
                       const float* __restrict__ gt_ctrl,
                       const int* __restrict__ gt_labels,
                       float* __restrict__ Cout) {
    const int bn = blockIdx.x;                  // b*N + n
    const int b  = bn >> 8;
    const int t  = threadIdx.x;
    const int lane = t & 63, wave = t >> 6;
    const float* rp = logits + (size_t)bn * CDIM;

    __shared__ float part[4];
    __shared__ float smax, ssum;

    float mx = -INF_F;
    for (int c = t; c < CDIM; c += 256) mx = fmaxf(mx, rp[c]);
    for (int off = 32; off; off >>= 1) mx = fmaxf(mx, __shfl_down(mx, off));
    if (lane == 0) part[wave] = mx;
    __syncthreads();
    if (t == 0) smax = fmaxf(fmaxf(part[0], part[1]), fmaxf(part[2], part[3]));
    __syncthreads();
    mx = smax;

    float s = 0.f;
    for (int c = t; c < CDIM; c += 256) s += expf(rp[c] - mx);
    for (int off = 32; off; off >>= 1) s += __shfl_down(s, off);
    __syncthreads();
    if (lane == 0) part[wave] = s;
    __syncthreads();
    if (t == 0) ssum = part[0] + part[1] + part[2] + part[3];
    __syncthreads();

    const float rmax = smax, rsum = ssum;
    const int m = t;

    const float* pp = pred_ctrl + (size_t)bn * 8;
    const float p0 = pp[0], p1 = pp[1], p2 = pp[2], p3 = pp[3];
    const float p4 = pp[4], p5 = pp[5], p6 = pp[6], p7 = pp[7];

    const float* gp = gt_ctrl + ((size_t)b * MCOL + m) * 8;
    const float4 ga = *(const float4*)gp;
    const float4 gb = *(const float4*)(gp + 4);

    const int lbl = gt_labels[b * MCOL + m];
    const float prob = expf(rp[lbl] - rmax) / rsum;

    float cb = fabsf(p0 - ga.x);
    cb += fabsf(p1 - ga.y);
    cb += fabsf(p2 - ga.z);
    cb += fabsf(p3 - ga.w);
    cb += fabsf(p4 - gb.x);
    cb += fabsf(p5 - gb.y);
    cb += fabsf(p6 - gb.z);
    cb += fabsf(p7 - gb.w);

    Cout[(size_t)bn * MCOL + m] = -prob + 5.0f * cb;
}

// ---------------------------------------------------------------------------
// Helpers: order-preserving float<->uint, DPP wave-min, readlane, select4
// ---------------------------------------------------------------------------
__device__ __forceinline__ unsigned ordkey(float f) {
    unsigned b = __float_as_uint(f);
    return (b & 0x80000000u) ? ~b : (b | 0x80000000u);
}
__device__ __forceinline__ float unordkey(unsigned k) {
    unsigned b = (k & 0x80000000u) ? (k ^ 0x80000000u) : ~k;
    return __uint_as_float(b);
}

template<int CTRL>
__device__ __forceinline__ unsigned dpp_min_step(unsigned x) {
    const unsigned o = (unsigned)__builtin_amdgcn_update_dpp((int)x, (int)x, CTRL, 0xf, 0xf, false);
    return o < x ? o : x;
}
// min over 64 lanes, result broadcast via SGPR (canonical row_shr/bcast chain)
__device__ __forceinline__ unsigned wave_min_u32(unsigned x) {
    x = dpp_min_step<0x111>(x);   // row_shr:1
    x = dpp_min_step<0x112>(x);   // row_shr:2
    x = dpp_min_step<0x114>(x);   // row_shr:4
    x = dpp_min_step<0x118>(x);   // row_shr:8
    x = dpp_min_step<0x142>(x);   // row_bcast:15
    x = dpp_min_step<0x143>(x);   // row_bcast:31
    return (unsigned)__builtin_amdgcn_readlane((int)x, 63);
}

__device__ __forceinline__ float readlane_f(float x, int lane_idx) {
    return __int_as_float(__builtin_amdgcn_readlane(__float_as_int(x), lane_idx));
}
__device__ __forceinline__ float sel4f(float a0, float a1, float a2, float a3, int s) {
    float r = a0;
    r = (s == 1) ? a1 : r;
    r = (s == 2) ? a2 : r;
    r = (s == 3) ? a3 : r;
    return r;
}
__device__ __forceinline__ int sel4i(int a0, int a1, int a2, int a3, int s) {
    int r = a0;
    r = (s == 1) ? a1 : r;
    r = (s == 2) ? a2 : r;
    r = (s == 3) ? a3 : r;
    return r;
}

// ---------------------------------------------------------------------------
// Kernel: lapjv-style LSA, one wave per batch. Lane t owns rows/cols 4t..4t+3.
// State (u, v, spc, row4col, col4row) lives in registers; argmin via DPP;
// cross-lane scalar reads via readlane (indices are wave-uniform).
// CR + 2x ARR init preserves dual feasibility + complementary slackness, so
// SAP phases converge to the same (unique) optimum as the reference.
// ---------------------------------------------------------------------------
__global__ __launch_bounds__(64)
void lsa_kernel(const float* __restrict__ Cmat,
                float* __restrict__ out_row,
                float* __restrict__ out_col) {
    const int b = blockIdx.x;
    const int t = threadIdx.x;
    const int jb = 4 * t;
    const float* C = Cmat + (size_t)b * NROW * MCOL;

    __shared__ int row4col_s[MCOL];
    __shared__ int col4row_s[NROW];
    __shared__ int path_s[MCOL];
    __shared__ int queue_s[NROW];
    __shared__ int argrow_s[MCOL];
    __shared__ int nfree_s;

    // ---------------- column reduction ----------------
    float m0 = INF_F, m1 = INF_F, m2 = INF_F, m3 = INF_F;
    int   r0 = 0, r1 = 0, r2 = 0, r3 = 0;
    for (int i = 0; i < NROW; i++) {
        const float4 c4 = *(const float4*)(C + (size_t)i * MCOL + jb);
        if (c4.x < m0) { m0 = c4.x; r0 = i; }
        if (c4.y < m1) { m1 = c4.y; r1 = i; }
        if (c4.z < m2) { m2 = c4.z; r2 = i; }
        if (c4.w < m3) { m3 = c4.w; r3 = i; }
    }
    float v0 = m0, v1 = m1, v2 = m2, v3 = m3;   // v[j], owner lane regs
    float u0 = 0.f, u1 = 0.f, u2 = 0.f, u3 = 0.f; // u[i], owner lane regs

    argrow_s[jb + 0] = r0; argrow_s[jb + 1] = r1;
    argrow_s[jb + 2] = r2; argrow_s[jb + 3] = r3;
    for (int k = 0; k < 4; k++) {
        row4col_s[jb + k] = -1;
        col4row_s[jb + k] = -1;
        path_s[jb + k] = -1;
    }
    __syncthreads();

    if (t == 0) {   // greedy tight matching on column minima
        for (int j = 0; j < MCOL; j++) {
            const int r = argrow_s[j];
            if (col4row_s[r] < 0) { col4row_s[r] = j; row4col_s[j] = r; }
        }
    }
    __syncthreads();

    int4 q;
    q = *(const int4*)&row4col_s[jb];
    int rc0 = q.x, rc1 = q.y, rc2 = q.z, rc3 = q.w;   // row4col mirror
    q = *(const int4*)&col4row_s[jb];
    int cr0 = q.x, cr1 = q.y, cr2 = q.z, cr3 = q.w;   // col4row mirror

    // ---------------- augmenting row reduction (2 rounds, budget-capped) ----
    int budget = 8 * NROW;
    for (int round = 0; round < 2; round++) {
        *(int4*)&col4row_s[jb] = make_int4(cr0, cr1, cr2, cr3);
        __syncthreads();
        if (t == 0) {
            int nf = 0;
            for (int i2 = 0; i2 < NROW; i2++)
                if (col4row_s[i2] < 0) queue_s[nf++] = i2;
            nfree_s = nf;
        }
        __syncthreads();
        const int nfr = __builtin_amdgcn_readfirstlane(nfree_s);
        if (nfr == 0) break;

        for (int qi = 0; qi < nfr && budget > 0; qi++) {
            int i = __builtin_amdgcn_readfirstlane(queue_s[qi]);
            while (i >= 0 && budget > 0) {
                budget--;
                const float4 c4 = *(const float4*)(C + (size_t)i * MCOL + jb);
                const float d0 = c4.x - v0, d1 = c4.y - v1;
                const float d2 = c4.z - v2, d3 = c4.w - v3;
                unsigned lmin; int lcol;
                {
                    const unsigned k0 = ordkey(d0), k1 = ordkey(d1);
                    const unsigned k2 = ordkey(d2), k3 = ordkey(d3);
                    lmin = k0; lcol = jb;
                    if (k1 < lmin) { lmin = k1; lcol = jb + 1; }
                    if (k2 < lmin) { lmin = k2; lcol = jb + 2; }
                    if (k3 < lmin) { lmin = k3; lcol = jb + 3; }
                }
                const unsigned g1 = wave_min_u32(lmin);
                const unsigned long long bal = __ballot(lmin == g1);
                const int w = __ffsll(bal) - 1;
                const int j1 = __builtin_amdgcn_readlane(lcol, w);
                const float mu1 = unordkey(g1);

                unsigned lmin2 = lmin;
                if ((j1 >> 2) == t) {     // winner lane: local min excluding j1
                    const int sl = j1 & 3; unsigned k;
                    lmin2 = 0xFFFFFFFFu;
                    if (sl != 0) { k = ordkey(d0); if (k < lmin2) lmin2 = k; }
                    if (sl != 1) { k = ordkey(d1); if (k < lmin2) lmin2 = k; }
                    if (sl != 2) { k = ordkey(d2); if (k < lmin2) lmin2 = k; }
                    if (sl != 3) { k = ordkey(d3); if (k < lmin2) lmin2 = k; }
                }
                const unsigned g2 = wave_min_u32(lmin2);
                const float mu2 = unordkey(g2);

                if ((i >> 2) == t) {      // u[i] = mu2
                    const int s = i & 3;
                    u0 = s == 0 ? mu2 : u0; u1 = s == 1 ? mu2 : u1;
                    u2 = s == 2 ? mu2 : u2; u3 = s == 3 ? mu2 : u3;
                }
                if ((j1 >> 2) == t && mu2 > mu1) {   // v[j1] -= (mu2-mu1)
                    const int s = j1 & 3; const float dv = mu2 - mu1;
                    v0 -= s == 0 ? dv : 0.f; v1 -= s == 1 ? dv : 0.f;
                    v2 -= s == 2 ? dv : 0.f; v3 -= s == 3 ? dv : 0.f;
                }
                const int kold = __builtin_amdgcn_readlane(
                    sel4i(rc0, rc1, rc2, rc3, j1 & 3), j1 >> 2);
                if ((j1 >> 2) == t) {     // row4col[j1] = i
                    const int s = j1 & 3;
                    rc0 = s == 0 ? i : rc0; rc1 = s == 1 ? i : rc1;
                    rc2 = s == 2 ? i : rc2; rc3 = s == 3 ? i : rc3;
                }
                if ((i >> 2) == t) {      // col4row[i] = j1
                    const int s = i & 3;
                    cr0 = s == 0 ? j1 : cr0; cr1 = s == 1 ? j1 : cr1;
                    cr2 = s == 2 ? j1 : cr2; cr3 = s == 3 ? j1 : cr3;
                }
                if (kold >= 0 && (kold >> 2) == t) {  // col4row[kold] = -1
                    const int s = kold & 3;
                    cr0 = s == 0 ? -1 : cr0; cr1 = s == 1 ? -1 : cr1;
                    cr2 = s == 2 ? -1 : cr2; cr3 = s == 3 ? -1 : cr3;
                }
                i = kold;   // continue chain with displaced row (or -1 done)
            }
        }
    }

    // dump matching, build SAP free-row queue
    *(int4*)&col4row_s[jb] = make_int4(cr0, cr1, cr2, cr3);
    *(int4*)&row4col_s[jb] = make_int4(rc0, rc1, rc2, rc3);
    __syncthreads();
    if (t == 0) {
        int nf = 0;
        for (int i2 = 0; i2 < NROW; i2++)
            if (col4row_s[i2] < 0) queue_s[nf++] = i2;
        nfree_s = nf;
    }
    __syncthreads();

    // ---------------- shortest augmenting path phases ----------------
    const int nphase = __builtin_amdgcn_readfirstlane(nfree_s);
    for (int ph = 0; ph < nphase; ph++) {
        const int cur = __builtin_amdgcn_readfirstlane(queue_s[ph]);
        q = *(const int4*)&row4col_s[jb];
        rc0 = q.x; rc1 = q.y; rc2 = q.z; rc3 = q.w;

        float s0 = INF_F, s1 = INF_F, s2 = INF_F, s3 = INF_F;  // spc
        float e0 = 0.f, e1 = 0.f, e2 = 0.f, e3 = 0.f;          // entering minVal
        int scmask = 0, srmask = 0;
        int i = cur, sink = -1;
        float minVal = 0.f;

        for (int it = 0; it < MCOL && sink < 0; it++) {
            if ((i >> 2) == t) srmask |= 1 << (i & 3);
            const float ui = readlane_f(sel4f(u0, u1, u2, u3, i & 3), i >> 2);
            const float4 c4 = *(const float4*)(C + (size_t)i * MCOL + jb);
            const float base = minVal - ui;
            float d;
            d = base + c4.x - v0; if (!(scmask & 1) && d < s0) { s0 = d; path_s[jb + 0] = i; }
            d = base + c4.y - v1; if (!(scmask & 2) && d < s1) { s1 = d; path_s[jb + 1] = i; }
            d = base + c4.z - v2; if (!(scmask & 4) && d < s2) { s2 = d; path_s[jb + 2] = i; }
            d = base + c4.w - v3; if (!(scmask & 8) && d < s3) { s3 = d; path_s[jb + 3] = i; }

            unsigned lmin = 0xFFFFFFFFu; int lcol = 0;
            if (!(scmask & 1)) { const unsigned k = ordkey(s0); if (k < lmin) { lmin = k; lcol = jb + 0; } }
            if (!(scmask & 2)) { const unsigned k = ordkey(s1); if (k < lmin) { lmin = k; lcol = jb + 1; } }
            if (!(scmask & 4)) { const unsigned k = ordkey(s2); if (k < lmin) { lmin = k; lcol = jb + 2; } }
            if (!(scmask & 8)) { const unsigned k = ordkey(s3); if (k < lmin) { lmin = k; lcol = jb + 3; } }

            const unsigned g = wave_min_u32(lmin);
            const unsigned long long bal = __ballot(lmin == g);
            const int w = __ffsll(bal) - 1;
            const int mj = __builtin_amdgcn_readlane(lcol, w);
            minVal = unordkey(g);

            if ((mj >> 2) == t) scmask |= 1 << (mj & 3);
            const int rc = __builtin_amdgcn_readlane(
                sel4i(rc0, rc1, rc2, rc3, mj & 3), mj >> 2);
            if (rc < 0) {
                sink = mj;
            } else {
                i = rc;
                if ((rc >> 2) == t) {     // record entering value for row rc
                    const int s = rc & 3;
                    e0 = s == 0 ? minVal : e0; e1 = s == 1 ? minVal : e1;
                    e2 = s == 2 ? minVal : e2; e3 = s == 3 ? minVal : e3;
                }
            }
        }

        // dual updates (same formulas as reference)
        if (srmask & 1) u0 += ((jb + 0) == cur) ? minVal : (minVal - e0);
        if (srmask & 2) u1 += ((jb + 1) == cur) ? minVal : (minVal - e1);
        if (srmask & 4) u2 += ((jb + 2) == cur) ? minVal : (minVal - e2);
        if (srmask & 8) u3 += ((jb + 3) == cur) ? minVal : (minVal - e3);
        if (scmask & 1) v0 -= (minVal - s0);
        if (scmask & 2) v1 -= (minVal - s1);
        if (scmask & 4) v2 -= (minVal - s2);
        if (scmask & 8) v3 -= (minVal - s3);

        __syncthreads();
        if (t == 0) {   // augment along predecessor path
            int j = sink;
            while (true) {
                const int ii = path_s[j];
                row4col_s[j] = ii;
                const int jn = col4row_s[ii];
                col4row_s[ii] = j;
                if (ii == cur) break;
                j = jn;
            }
        }
        __syncthreads();
    }

    for (int k = 0; k < 4; k++) {
        const int idx = jb + k;
        out_row[b * NROW + idx] = (float)idx;
        out_col[b * NROW + idx] = (float)col4row_s[idx];
    }
}

// ---------------------------------------------------------------------------
extern "C" void kernel_launch(void* const* d_in, const int* in_sizes, int n_in,
                              void* d_out, int out_size, void* d_ws, size_t ws_size,
                              hipStream_t stream) {
    const float* pred_ctrl   = (const float*)d_in[0];
    const float* pred_logits = (const float*)d_in[1];
    const float* gt_ctrl     = (const float*)d_in[2];
    const int*   gt_labels   = (const int*)d_in[3];

    float* out     = (float*)d_out;
    float* out_row = out;
    float* out_col = out + BATCH * NROW;
    float* Cout    = out + 2 * BATCH * NROW;

    cost_fused_kernel<<<BATCH * NROW, 256, 0, stream>>>(pred_ctrl, pred_logits,
                                                        gt_ctrl, gt_labels, Cout);
    lsa_kernel<<<BATCH, 64, 0, stream>>>(Cout, out_row, out_col);
}

// Round 4
// 2133.887 us; speedup vs baseline: 4.8939x; 1.0481x over previous
//
#include <hip/hip_runtime.h>

#define BATCH 16
#define NROW  256
#define MCOL  256
#define CDIM  4096
#define INF_F 1e30f
#define CROWS 144   // rows of C cached in LDS (144*256*4 = 147456 B)

// ---------------------------------------------------------------------------
// Fused cost kernel: per-(b,n) softmax stats over C=4096, then 256 cost cols.
// cost[b,n,m] = -softmax(logits[b,n])[lbl[b,m]] + 5 * L1(p[b,n], g[b,m])
// ---------------------------------------------------------------------------
__global__ __launch_bounds__(256)
void cost_fused_kernel(const float* __restrict__ pred_ctrl,
                       const float* __restrict__ logits,
                       const float* __restrict__ gt_ctrl,
                       const int* __restrict__ gt_labels,
                       float* __restrict__ Cout) {
    const int bn = blockIdx.x;                  // b*N + n
    const int b  = bn >> 8;
    const int t  = threadIdx.x;
    const int lane = t & 63, wave = t >> 6;
    const float* rp = logits + (size_t)bn * CDIM;

    __shared__ float part[4];
    __shared__ float smax, ssum;

    float mx = -INF_F;
    for (int c = t; c < CDIM; c += 256) mx = fmaxf(mx, rp[c]);
    for (int off = 32; off; off >>= 1) mx = fmaxf(mx, __shfl_down(mx, off));
    if (lane == 0) part[wave] = mx;
    __syncthreads();
    if (t == 0) smax = fmaxf(fmaxf(part[0], part[1]), fmaxf(part[2], part[3]));
    __syncthreads();
    mx = smax;

    float s = 0.f;
    for (int c = t; c < CDIM; c += 256) s += expf(rp[c] - mx);
    for (int off = 32; off; off >>= 1) s += __shfl_down(s, off);
    __syncthreads();
    if (lane == 0) part[wave] = s;
    __syncthreads();
    if (t == 0) ssum = part[0] + part[1] + part[2] + part[3];
    __syncthreads();

    const float rmax = smax, rsum = ssum;
    const int m = t;

    const float* pp = pred_ctrl + (size_t)bn * 8;
    const float p0 = pp[0], p1 = pp[1], p2 = pp[2], p3 = pp[3];
    const float p4 = pp[4], p5 = pp[5], p6 = pp[6], p7 = pp[7];

    const float* gp = gt_ctrl + ((size_t)b * MCOL + m) * 8;
    const float4 ga = *(const float4*)gp;
    const float4 gb = *(const float4*)(gp + 4);

    const int lbl = gt_labels[b * MCOL + m];
    const float prob = expf(rp[lbl] - rmax) / rsum;

    float cb = fabsf(p0 - ga.x);
    cb += fabsf(p1 - ga.y);
    cb += fabsf(p2 - ga.z);
    cb += fabsf(p3 - ga.w);
    cb += fabsf(p4 - gb.x);
    cb += fabsf(p5 - gb.y);
    cb += fabsf(p6 - gb.z);
    cb += fabsf(p7 - gb.w);

    Cout[(size_t)bn * MCOL + m] = -prob + 5.0f * cb;
}

// ---------------------------------------------------------------------------
// Helpers: order-preserving float<->uint, DPP wave-min, readlane, select4
// ---------------------------------------------------------------------------
__device__ __forceinline__ unsigned ordkey(float f) {
    unsigned b = __float_as_uint(f);
    return (b & 0x80000000u) ? ~b : (b | 0x80000000u);
}
__device__ __forceinline__ float unordkey(unsigned k) {
    unsigned b = (k & 0x80000000u) ? (k ^ 0x80000000u) : ~k;
    return __uint_as_float(b);
}

template<int CTRL>
__device__ __forceinline__ unsigned dpp_min_step(unsigned x) {
    const unsigned o = (unsigned)__builtin_amdgcn_update_dpp((int)x, (int)x, CTRL, 0xf, 0xf, false);
    return o < x ? o : x;
}
// min over 64 lanes, result broadcast via SGPR (canonical row_shr/bcast chain)
__device__ __forceinline__ unsigned wave_min_u32(unsigned x) {
    x = dpp_min_step<0x111>(x);   // row_shr:1
    x = dpp_min_step<0x112>(x);   // row_shr:2
    x = dpp_min_step<0x114>(x);   // row_shr:4
    x = dpp_min_step<0x118>(x);   // row_shr:8
    x = dpp_min_step<0x142>(x);   // row_bcast:15
    x = dpp_min_step<0x143>(x);   // row_bcast:31
    return (unsigned)__builtin_amdgcn_readlane((int)x, 63);
}

__device__ __forceinline__ float readlane_f(float x, int lane_idx) {
    return __int_as_float(__builtin_amdgcn_readlane(__float_as_int(x), lane_idx));
}
__device__ __forceinline__ float sel4f(float a0, float a1, float a2, float a3, int s) {
    float r = a0;
    r = (s == 1) ? a1 : r;
    r = (s == 2) ? a2 : r;
    r = (s == 3) ? a3 : r;
    return r;
}
__device__ __forceinline__ int sel4i(int a0, int a1, int a2, int a3, int s) {
    int r = a0;
    r = (s == 1) ? a1 : r;
    r = (s == 2) ? a2 : r;
    r = (s == 3) ? a3 : r;
    return r;
}

// ---------------------------------------------------------------------------
// Kernel: lapjv-style LSA, one wave per batch. Lane t owns rows/cols 4t..4t+3.
// Rows 0..CROWS-1 of C are cached in LDS (exact fp32 copies) to cut the
// dependent row-load latency (~210 cyc L2 -> ~120 cyc LDS).
// State (u, v, spc, row4col, col4row) lives in registers; argmin via DPP;
// winner lane returns (slot, matched-row) packed in ONE readlane.
// CR + 2x ARR init preserves dual feasibility + complementary slackness, so
// SAP phases converge to the same (unique) optimum as the reference.
// ---------------------------------------------------------------------------
__global__ __launch_bounds__(64)
void lsa_kernel(const float* __restrict__ Cmat,
                float* __restrict__ out_row,
                float* __restrict__ out_col) {
    const int b = blockIdx.x;
    const int t = threadIdx.x;
    const int jb = 4 * t;
    const float* C = Cmat + (size_t)b * NROW * MCOL;

    __shared__ float Cc[CROWS][MCOL];          // 147456 B row cache
    __shared__ int row4col_s[MCOL];
    __shared__ int col4row_s[NROW];
    __shared__ int path_s[MCOL];
    __shared__ int queue_s[NROW];
    __shared__ int argrow_s[MCOL];
    __shared__ int nfree_s;

    // ---------------- column reduction + LDS row staging ----------------
    float m0 = INF_F, m1 = INF_F, m2 = INF_F, m3 = INF_F;
    int   r0 = 0, r1 = 0, r2 = 0, r3 = 0;
    for (int i = 0; i < NROW; i++) {
        const float4 c4 = *(const float4*)(C + (size_t)i * MCOL + jb);
        if (i < CROWS) *(float4*)&Cc[i][jb] = c4;
        if (c4.x < m0) { m0 = c4.x; r0 = i; }
        if (c4.y < m1) { m1 = c4.y; r1 = i; }
        if (c4.z < m2) { m2 = c4.z; r2 = i; }
        if (c4.w < m3) { m3 = c4.w; r3 = i; }
    }
    float v0 = m0, v1 = m1, v2 = m2, v3 = m3;     // v[j], owner lane regs
    float u0 = 0.f, u1 = 0.f, u2 = 0.f, u3 = 0.f; // u[i], owner lane regs

    argrow_s[jb + 0] = r0; argrow_s[jb + 1] = r1;
    argrow_s[jb + 2] = r2; argrow_s[jb + 3] = r3;
    for (int k = 0; k < 4; k++) {
        row4col_s[jb + k] = -1;
        col4row_s[jb + k] = -1;
        path_s[jb + k] = -1;
    }
    __syncthreads();

    if (t == 0) {   // greedy tight matching on column minima
        for (int j = 0; j < MCOL; j++) {
            const int r = argrow_s[j];
            if (col4row_s[r] < 0) { col4row_s[r] = j; row4col_s[j] = r; }
        }
    }
    __syncthreads();

    int4 q;
    q = *(const int4*)&row4col_s[jb];
    int rc0 = q.x, rc1 = q.y, rc2 = q.z, rc3 = q.w;   // row4col mirror
    q = *(const int4*)&col4row_s[jb];
    int cr0 = q.x, cr1 = q.y, cr2 = q.z, cr3 = q.w;   // col4row mirror

    // ---------------- augmenting row reduction (2 rounds, budget-capped) ----
    int budget = 8 * NROW;
    for (int round = 0; round < 2; round++) {
        *(int4*)&col4row_s[jb] = make_int4(cr0, cr1, cr2, cr3);
        __syncthreads();
        if (t == 0) {
            int nf = 0;
            for (int i2 = 0; i2 < NROW; i2++)
                if (col4row_s[i2] < 0) queue_s[nf++] = i2;
            nfree_s = nf;
        }
        __syncthreads();
        const int nfr = __builtin_amdgcn_readfirstlane(nfree_s);
        if (nfr == 0) break;

        for (int qi = 0; qi < nfr && budget > 0; qi++) {
            int i = __builtin_amdgcn_readfirstlane(queue_s[qi]);
            while (i >= 0 && budget > 0) {
                budget--;
                float4 c4;
                if (i < CROWS) c4 = *(const float4*)&Cc[i][jb];
                else           c4 = *(const float4*)(C + (size_t)i * MCOL + jb);
                const float d0 = c4.x - v0, d1 = c4.y - v1;
                const float d2 = c4.z - v2, d3 = c4.w - v3;
                // local argmin over 4, carrying slot + matched row
                unsigned lmin; int lslot, lrc;
                {
                    const unsigned k0 = ordkey(d0), k1 = ordkey(d1);
                    const unsigned k2 = ordkey(d2), k3 = ordkey(d3);
                    lmin = k0; lslot = 0; lrc = rc0;
                    if (k1 < lmin) { lmin = k1; lslot = 1; lrc = rc1; }
                    if (k2 < lmin) { lmin = k2; lslot = 2; lrc = rc2; }
                    if (k3 < lmin) { lmin = k3; lslot = 3; lrc = rc3; }
                }
                const unsigned g1 = wave_min_u32(lmin);
                const unsigned long long bal = __ballot(lmin == g1);
                const int w = __ffsll(bal) - 1;
                const int pk = __builtin_amdgcn_readlane(((lrc + 1) << 2) | lslot, w);
                const int j1 = 4 * w + (pk & 3);
                const int kold = (pk >> 2) - 1;
                const float mu1 = unordkey(g1);

                unsigned lmin2 = lmin;
                if (w == t) {     // winner lane: local min excluding j1's slot
                    const int sl = pk & 3; unsigned k;
                    lmin2 = 0xFFFFFFFFu;
                    if (sl != 0) { k = ordkey(d0); if (k < lmin2) lmin2 = k; }
                    if (sl != 1) { k = ordkey(d1); if (k < lmin2) lmin2 = k; }
                    if (sl != 2) { k = ordkey(d2); if (k < lmin2) lmin2 = k; }
                    if (sl != 3) { k = ordkey(d3); if (k < lmin2) lmin2 = k; }
                }
                const unsigned g2 = wave_min_u32(lmin2);
                const float mu2 = unordkey(g2);

                if ((i >> 2) == t) {      // u[i] = mu2
                    const int s = i & 3;
                    u0 = s == 0 ? mu2 : u0; u1 = s == 1 ? mu2 : u1;
                    u2 = s == 2 ? mu2 : u2; u3 = s == 3 ? mu2 : u3;
                }
                if (w == t && mu2 > mu1) {   // v[j1] -= (mu2-mu1)
                    const int s = pk & 3; const float dv = mu2 - mu1;
                    v0 -= s == 0 ? dv : 0.f; v1 -= s == 1 ? dv : 0.f;
                    v2 -= s == 2 ? dv : 0.f; v3 -= s == 3 ? dv : 0.f;
                }
                if (w == t) {     // row4col[j1] = i
                    const int s = pk & 3;
                    rc0 = s == 0 ? i : rc0; rc1 = s == 1 ? i : rc1;
                    rc2 = s == 2 ? i : rc2; rc3 = s == 3 ? i : rc3;
                }
                if ((i >> 2) == t) {      // col4row[i] = j1
                    const int s = i & 3;
                    cr0 = s == 0 ? j1 : cr0; cr1 = s == 1 ? j1 : cr1;
                    cr2 = s == 2 ? j1 : cr2; cr3 = s == 3 ? j1 : cr3;
                }
                if (kold >= 0 && (kold >> 2) == t) {  // col4row[kold] = -1
                    const int s = kold & 3;
                    cr0 = s == 0 ? -1 : cr0; cr1 = s == 1 ? -1 : cr1;
                    cr2 = s == 2 ? -1 : cr2; cr3 = s == 3 ? -1 : cr3;
                }
                i = kold;   // continue chain with displaced row (or -1 done)
            }
        }
    }

    // dump matching, build SAP free-row queue
    *(int4*)&col4row_s[jb] = make_int4(cr0, cr1, cr2, cr3);
    *(int4*)&row4col_s[jb] = make_int4(rc0, rc1, rc2, rc3);
    __syncthreads();
    if (t == 0) {
        int nf = 0;
        for (int i2 = 0; i2 < NROW; i2++)
            if (col4row_s[i2] < 0) queue_s[nf++] = i2;
        nfree_s = nf;
    }
    __syncthreads();

    // ---------------- shortest augmenting path phases ----------------
    const int nphase = __builtin_amdgcn_readfirstlane(nfree_s);
    for (int ph = 0; ph < nphase; ph++) {
        const int cur = __builtin_amdgcn_readfirstlane(queue_s[ph]);
        q = *(const int4*)&row4col_s[jb];           // phase-constant mirror
        rc0 = q.x; rc1 = q.y; rc2 = q.z; rc3 = q.w;

        float s0 = INF_F, s1 = INF_F, s2 = INF_F, s3 = INF_F;  // spc
        float e0 = 0.f, e1 = 0.f, e2 = 0.f, e3 = 0.f;          // entering minVal
        int scmask = 0, srmask = 0;
        int i = cur, sink = -1;
        float minVal = 0.f;

        for (int it = 0; it < MCOL && sink < 0; it++) {
            if ((i >> 2) == t) srmask |= 1 << (i & 3);
            const float ui = readlane_f(sel4f(u0, u1, u2, u3, i & 3), i >> 2);
            float4 c4;
            if (i < CROWS) c4 = *(const float4*)&Cc[i][jb];
            else           c4 = *(const float4*)(C + (size_t)i * MCOL + jb);
            const float base = minVal - ui;
            float d;
            d = base + c4.x - v0; if (!(scmask & 1) && d < s0) { s0 = d; path_s[jb + 0] = i; }
            d = base + c4.y - v1; if (!(scmask & 2) && d < s1) { s1 = d; path_s[jb + 1] = i; }
            d = base + c4.z - v2; if (!(scmask & 4) && d < s2) { s2 = d; path_s[jb + 2] = i; }
            d = base + c4.w - v3; if (!(scmask & 8) && d < s3) { s3 = d; path_s[jb + 3] = i; }

            // local argmin over unvisited owned cols, carrying slot + matched row
            unsigned lmin = 0xFFFFFFFFu; int lslot = 0, lrc = -1;
            if (!(scmask & 1)) { const unsigned k = ordkey(s0); if (k < lmin) { lmin = k; lslot = 0; lrc = rc0; } }
            if (!(scmask & 2)) { const unsigned k = ordkey(s1); if (k < lmin) { lmin = k; lslot = 1; lrc = rc1; } }
            if (!(scmask & 4)) { const unsigned k = ordkey(s2); if (k < lmin) { lmin = k; lslot = 2; lrc = rc2; } }
            if (!(scmask & 8)) { const unsigned k = ordkey(s3); if (k < lmin) { lmin = k; lslot = 3; lrc = rc3; } }

            const unsigned g = wave_min_u32(lmin);
            const unsigned long long bal = __ballot(lmin == g);
            const int w = __ffsll(bal) - 1;
            const int pk = __builtin_amdgcn_readlane(((lrc + 1) << 2) | lslot, w);
            const int mj = 4 * w + (pk & 3);
            const int rc = (pk >> 2) - 1;
            minVal = unordkey(g);

            if (w == t) scmask |= 1 << (pk & 3);
            if (rc < 0) {
                sink = mj;
            } else {
                i = rc;
                if ((rc >> 2) == t) {     // record entering value for row rc
                    const int s = rc & 3;
                    e0 = s == 0 ? minVal : e0; e1 = s == 1 ? minVal : e1;
                    e2 = s == 2 ? minVal : e2; e3 = s == 3 ? minVal : e3;
                }
            }
        }

        // dual updates (same formulas as reference)
        if (srmask & 1) u0 += ((jb + 0) == cur) ? minVal : (minVal - e0);
        if (srmask & 2) u1 += ((jb + 1) == cur) ? minVal : (minVal - e1);
        if (srmask & 4) u2 += ((jb + 2) == cur) ? minVal : (minVal - e2);
        if (srmask & 8) u3 += ((jb + 3) == cur) ? minVal : (minVal - e3);
        if (scmask & 1) v0 -= (minVal - s0);
        if (scmask & 2) v1 -= (minVal - s1);
        if (scmask & 4) v2 -= (minVal - s2);
        if (scmask & 8) v3 -= (minVal - s3);

        __syncthreads();
        if (t == 0) {   // augment along predecessor path
            int j = sink;
            while (true) {
                const int ii = path_s[j];
                row4col_s[j] = ii;
                const int jn = col4row_s[ii];
                col4row_s[ii] = j;
                if (ii == cur) break;
                j = jn;
            }
        }
        __syncthreads();
    }

    for (int k = 0; k < 4; k++) {
        const int idx = jb + k;
        out_row[b * NROW + idx] = (float)idx;
        out_col[b * NROW + idx] = (float)col4row_s[idx];
    }
}

// ---------------------------------------------------------------------------
extern "C" void kernel_launch(void* const* d_in, const int* in_sizes, int n_in,
                              void* d_out, int out_size, void* d_ws, size_t ws_size,
                              hipStream_t stream) {
    const float* pred_ctrl   = (const float*)d_in[0];
    const float* pred_logits = (const float*)d_in[1];
    const float* gt_ctrl     = (const float*)d_in[2];
    const int*   gt_labels   = (const int*)d_in[3];

    float* out     = (float*)d_out;
    float* out_row = out;
    float* out_col = out + BATCH * NROW;
    float* Cout    = out + 2 * BATCH * NROW;

    cost_fused_kernel<<<BATCH * NROW, 256, 0, stream>>>(pred_ctrl, pred_logits,
                                                        gt_ctrl, gt_labels, Cout);
    lsa_kernel<<<BATCH, 64, 0, stream>>>(Cout, out_row, out_col);
}